// Round 9
// baseline (1225.682 us; speedup 1.0000x reference)
//
#include <hip/hip_runtime.h>

// MaxUnpooling2D B=16,H=128,W=128,C=64 -> out (16,256,256,64) f32 scatter-add.
// Full output index g = (batch<<22) | (mask & ~63) | (i & 63)  (26 bits).
//
// v10: FUSED producer-consumer persistent kernel (512 blocks, 2/CU).
//  Producer: r6's verified chunk sort (rank-merged histogram, single-wave
//    shfl scan, NT inputs, ALIGNED paired pass-C copy-out to uint2 segments).
//    Chunks claimed ascending -> batches complete in order. After each chunk:
//    __threadfence (agent release) + batch_done[b]++.
//  Consumer: r6's verified tile replay (uint4 pair prefetch, 64 KiB LDS tile
//    zero + LDS-atomic replay, NT float4 tile write). Tiles claimed ascending;
//    tid0 acquire-spins until the tile's batch has all 128 chunks done.
//  Tile fi only needs batch fi>>8 -> batch-0 tiles overlap batch-15 sorting,
//  removing the p1|p3 dispatch barrier (the last structural serialization).
//  Deadlock-free: claimed chunks are owned by running blocks that need no
//  shared resources to finish; spinners wait only on in-flight chunks.
//  P4: statistical-overflow spills applied with global atomics (LAST).

typedef int      vi4 __attribute__((ext_vector_type(4)));
typedef float    vf4 __attribute__((ext_vector_type(4)));
typedef unsigned vu4 __attribute__((ext_vector_type(4)));

constexpr int N      = 1 << 24;        // 16,777,216 updates
constexpr int FSHIFT = 14;             // fine tile: 16384 elems = 64 KiB
constexpr int NB     = 256;            // fine bins per batch (per chunk-block)
constexpr int NFINE  = 4096;           // fine bins total (16 batches * 256)
constexpr int CHUNK  = 8192;           // records per chunk (64 KiB staging)
constexpr int NCHUNK = N / CHUNK;      // 2048 chunks (128 per batch)
constexpr int FCAP   = 4608;           // segment capacity (mean ~4160 + ~7 sigma)
constexpr unsigned TM = (1u << FSHIFT) - 1u;
constexpr unsigned OVF_CAP = 131072;
constexpr int GRID   = 512;            // persistent blocks

// workspace layout
constexpr size_t GC_OFF   = 0;                               // 4096 u32 = 16 KiB
constexpr size_t CTR_OFF  = (size_t)NFINE * 4;               // 16384
// ctrs: [0]=ovf_cnt [1]=chunk_ctr [2]=tile_ctr [8..23]=batch_done[16]
constexpr size_t OVF_OFF  = CTR_OFF + 128;                   // 16512
constexpr size_t REC_OFF  = OVF_OFF + (size_t)OVF_CAP * 8;   // 1,065,088 (16B-al)
constexpr size_t WS_NEED  = REC_OFF + (size_t)NFINE * FCAP * 8;  // ~152 MB

__device__ __forceinline__ void spill(unsigned* ovf_cnt, uint2* ovf,
                                      unsigned g, unsigned v) {
    unsigned oi = atomicAdd(ovf_cnt, 1u);
    if (oi < OVF_CAP) ovf[oi] = make_uint2(g, v);
}

__global__ __launch_bounds__(512, 4) void fused(
        const float* __restrict__ upd, const int* __restrict__ msk,
        unsigned* __restrict__ gcnt, unsigned* __restrict__ ctrs,
        uint2* __restrict__ recs, uint2* __restrict__ ovf,
        float* __restrict__ out) {
    __shared__ uint2 sorted[CHUNK];                       // 64 KiB (= tile)
    __shared__ unsigned hist[NB], startx[NB], ends[NB], gbase[NB];
    __shared__ unsigned bcast;
    const int tid = threadIdx.x;
    unsigned* ovf_cnt    = ctrs + 0;
    unsigned* chunk_ctr  = ctrs + 1;
    unsigned* tile_ctr   = ctrs + 2;
    unsigned* batch_done = ctrs + 8;

    // ================= producer: chunk sort =================
    for (;;) {
        __syncthreads();                                  // protect bcast/LDS
        if (tid == 0) bcast = atomicAdd(chunk_ctr, 1u);
        if (tid < NB) hist[tid] = 0;
        __syncthreads();
        unsigned ca = bcast;
        if (ca >= (unsigned)NCHUNK) break;
        const unsigned batch = ca >> 7;                   // 128 chunks/batch
        const int q0 = (int)ca * (CHUNK / 4);             // base float4 index
        unsigned g[16];                                   // decoded out indices
        unsigned rank[16];                                // per-record rank in bin
        vf4 u[4];                                         // values (registers)

        // pass A: NT load mask+updates; decode + RANKING histogram.
#pragma unroll
        for (int k = 0; k < 4; ++k) {
            int q = q0 + k * 512 + tid;
            vi4 m = __builtin_nontemporal_load((const vi4*)msk + q);
            u[k]  = __builtin_nontemporal_load((const vf4*)upd + q);
            int i = q << 2;
            unsigned gb = ((unsigned)(i >> 20) << 22) | (unsigned)(i & 63);
            g[4 * k + 0] = (gb + 0) | (unsigned)(m.x & ~63);
            g[4 * k + 1] = (gb + 1) | (unsigned)(m.y & ~63);
            g[4 * k + 2] = (gb + 2) | (unsigned)(m.z & ~63);
            g[4 * k + 3] = (gb + 3) | (unsigned)(m.w & ~63);
#pragma unroll
            for (int e = 0; e < 4; ++e)
                rank[4 * k + e] =
                    atomicAdd(&hist[(g[4 * k + e] >> FSHIFT) & (NB - 1)], 1u);
        }
        __syncthreads();
        // gbase reservation (EVEN counts -> 16B-aligned pair stores).
        if (tid < NB)
            gbase[tid] = atomicAdd(&gcnt[batch * NB + tid],
                                   (hist[tid] + 1u) & ~1u);
        // single-wave exclusive scan over NB=256 bins (4 bins/lane, shfl_up).
        if (tid < 64) {
            unsigned h0 = hist[4 * tid + 0], h1 = hist[4 * tid + 1];
            unsigned h2 = hist[4 * tid + 2], h3 = hist[4 * tid + 3];
            unsigned s1 = h0 + h1, s2 = s1 + h2, tot = s2 + h3;
            unsigned incl = tot;
#pragma unroll
            for (int d = 1; d < 64; d <<= 1) {
                unsigned t = __shfl_up(incl, d, 64);
                if (tid >= d) incl += t;
            }
            unsigned base = incl - tot;                   // exclusive base
            startx[4 * tid + 0] = base;
            startx[4 * tid + 1] = base + h0;
            startx[4 * tid + 2] = base + s1;
            startx[4 * tid + 3] = base + s2;
            ends[4 * tid + 0]   = base + h0;
            ends[4 * tid + 1]   = base + s1;
            ends[4 * tid + 2]   = base + s2;
            ends[4 * tid + 3]   = base + tot;
        }
        __syncthreads();
        // pass B: atomic-free placement from registers
#pragma unroll
        for (int k = 0; k < 4; ++k) {
            float v[4] = { u[k].x, u[k].y, u[k].z, u[k].w };
#pragma unroll
            for (int e = 0; e < 4; ++e) {
                unsigned gg = g[4 * k + e];
                unsigned c = (gg >> FSHIFT) & (NB - 1);
                sorted[startx[c] + rank[4 * k + e]] =
                    make_uint2(gg, __float_as_uint(v[e]));
            }
        }
        __syncthreads();
        // pass C: ALIGNED paired copy-out (even run-relative offsets own the
        // pair; odd-length runs pad with dummy +0.0f same-tile record).
        for (int j = tid; j < CHUNK; j += 512) {
            uint2 r0 = sorted[j];
            unsigned f = r0.x >> FSHIFT;                  // global fine id
            unsigned c = f & (NB - 1);
            unsigned rro = (unsigned)j - startx[c];
            if (rro & 1u) continue;                       // partner of j-1
            unsigned s = gbase[c] + rro;                  // even
            bool pair = ((unsigned)(j + 1) < ends[c]);    // j+1 in same run
            uint2 r1 = pair ? sorted[j + 1] : make_uint2(r0.x, 0u);
            if (s + 1 < (unsigned)FCAP) {
                vu4 rr; rr.x = r0.x; rr.y = r0.y; rr.z = r1.x; rr.w = r1.y;
                *(vu4*)(recs + (size_t)f * FCAP + s) = rr;  // 16B-aligned
            } else {
                if (s < (unsigned)FCAP) recs[(size_t)f * FCAP + s] = r0;
                else spill(ovf_cnt, ovf, r0.x, r0.y);
                if (pair) spill(ovf_cnt, ovf, r1.x, r1.y);
            }
        }
        // release: recs stores visible device-wide before the batch signal.
        __threadfence();
        __syncthreads();
        if (tid == 0) atomicAdd(&batch_done[batch], 1u);
    }

    // ================= consumer: tile replay =================
    float* tile = (float*)sorted;                         // LDS reuse
    for (;;) {
        __syncthreads();                                  // protect bcast/tile
        if (tid == 0) {
            unsigned fi = atomicAdd(tile_ctr, 1u);
            if (fi < (unsigned)NFINE) {
                unsigned b = fi >> 8;                     // 256 tiles/batch
                while (__hip_atomic_load(&batch_done[b], __ATOMIC_ACQUIRE,
                                         __HIP_MEMORY_SCOPE_AGENT) < 128u)
                    __builtin_amdgcn_s_sleep(8);
            }
            bcast = fi;
        }
        __syncthreads();
        unsigned fi = bcast;
        if (fi >= (unsigned)NFINE) break;
        const int n = (int)min(gcnt[fi], (unsigned)FCAP); // always even
        const vu4* __restrict__ seg4 = (const vu4*)(recs + (size_t)fi * FCAP);

        // prefetch segment as record-PAIRS into registers (static indexing);
        // loads fill while we zero the tile below.
        vu4 ra, rb, rc, rd, re;
#define PF(R, K) { int ii = tid + (K) * 512;                                   \
        if (2 * ii < n) R = seg4[ii]; }
        PF(ra, 0) PF(rb, 1) PF(rc, 2) PF(rd, 3) PF(re, 4)
#undef PF
        vf4* t4 = (vf4*)tile;
        const vf4 z4 = { 0.f, 0.f, 0.f, 0.f };
#pragma unroll
        for (int k = 0; k < (1 << FSHIFT) / 4 / 512; ++k) // 8 float4 iters
            t4[tid + k * 512] = z4;
        __syncthreads();
#define RP(R, K) { int ii = tid + (K) * 512;                                   \
        if (2 * ii < n) {                                                      \
            atomicAdd(&tile[R.x & TM], __uint_as_float(R.y));                  \
            atomicAdd(&tile[R.z & TM], __uint_as_float(R.w)); } }
        RP(ra, 0) RP(rb, 1) RP(rc, 2) RP(rd, 3) RP(re, 4)
#undef RP
        __syncthreads();
        vf4* o = (vf4*)(out + ((size_t)fi << FSHIFT));
#pragma unroll
        for (int k = 0; k < (1 << FSHIFT) / 4 / 512; ++k)
            __builtin_nontemporal_store(t4[tid + k * 512], o + tid + k * 512);
    }
}

__global__ __launch_bounds__(256) void p4(const unsigned* __restrict__ ctrs,
                                          const uint2* __restrict__ ovf,
                                          float* __restrict__ out) {
    unsigned n = min(ctrs[0], OVF_CAP);
    for (unsigned i = blockIdx.x * 256 + threadIdx.x; i < n; i += gridDim.x * 256)
        atomicAdd(out + ovf[i].x, __uint_as_float(ovf[i].y));
}

// ---- fallback (ws too small): known-correct direct path ----
__global__ __launch_bounds__(256) void zero_out(float4* __restrict__ out4) {
    size_t i = (size_t)blockIdx.x * 256 + threadIdx.x;
    size_t stride = (size_t)gridDim.x * 256;
    for (size_t k = i; k < (size_t)N; k += stride)
        out4[k] = make_float4(0.f, 0.f, 0.f, 0.f);
}
__global__ __launch_bounds__(256) void unpool_scatter(
        const float4* __restrict__ upd4, const int4* __restrict__ msk4,
        float* __restrict__ out) {
    int i4 = blockIdx.x * 256 + threadIdx.x;
    int i  = i4 << 2;
    float4 u = upd4[i4];
    int4   m = msk4[i4];
    float* outb = out + ((size_t)(i >> 20) << 22);
    int f = i & 63;
    atomicAdd(outb + ((m.x & ~63) | (f + 0)), u.x);
    atomicAdd(outb + ((m.y & ~63) | (f + 1)), u.y);
    atomicAdd(outb + ((m.z & ~63) | (f + 2)), u.z);
    atomicAdd(outb + ((m.w & ~63) | (f + 3)), u.w);
}

extern "C" void kernel_launch(void* const* d_in, const int* in_sizes, int n_in,
                              void* d_out, int out_size, void* d_ws, size_t ws_size,
                              hipStream_t stream) {
    const float* updates = (const float*)d_in[0];
    const int*   mask    = (const int*)d_in[1];
    float*       out     = (float*)d_out;

    if (ws_size >= WS_NEED) {
        char* ws = (char*)d_ws;
        unsigned* gcnt = (unsigned*)(ws + GC_OFF);
        unsigned* ctrs = (unsigned*)(ws + CTR_OFF);
        uint2*    ovf  = (uint2*)(ws + OVF_OFF);
        uint2*    recs = (uint2*)(ws + REC_OFF);

        (void)hipMemsetAsync(ws, 0, OVF_OFF, stream);     // gcnt + ctrs
        fused<<<GRID, 512, 0, stream>>>(updates, mask, gcnt, ctrs, recs, ovf, out);
        p4<<<64, 256, 0, stream>>>(ctrs, ovf, out);       // spills LAST
    } else {
        zero_out<<<8192, 256, 0, stream>>>((float4*)out);
        unpool_scatter<<<N / 4 / 256, 256, 0, stream>>>(
            (const float4*)updates, (const int4*)mask, out);
    }
}

// Round 10
// 443.017 us; speedup vs baseline: 2.7667x; 2.7667x over previous
//
#include <hip/hip_runtime.h>

// MaxUnpooling2D B=16,H=128,W=128,C=64 -> out (16,256,256,64) f32 scatter-add.
// Full output index g = (batch<<22) | (mask & ~63) | (i & 63)  (26 bits).
//
// FINAL (v11 = r6 revert, best verified 443.6 us):
//  P1: block-local counting sort of 8192-record chunks into 256 fine bins
//      (fine bin = 16384-elem = 64 KiB out tile). Rank-merged histogram
//      (atomicAdd returns per-record rank -> pass B places with no atomics),
//      single-wave shfl scan, NT input loads, ALIGNED paired pass-C copy-out
//      (even gbase reservations; dummy +0.0f pad for odd runs) -> one 16B
//      store per 2 records.
//  P3: one block (512 thr) per fine bin: segment prefetched as uint4 pairs
//      into registers before/while zeroing the 64 KiB LDS tile, LDS-atomic
//      replay, dense NT float4 tile write (covers whole output).
//  P4: statistical-overflow spills applied with global atomics (LAST).
//
// Session evidence (r5-r9): LDS-atomic removal null; occupancy bound null;
// SoA 6B records null; fused producer-consumer (cross-XCD handoff) -2.8x
// (coherence fences/invalidate spin -> 7% HBM util). This two-dispatch
// structure is the measured practical floor of the design space explored.

typedef int      vi4 __attribute__((ext_vector_type(4)));
typedef float    vf4 __attribute__((ext_vector_type(4)));
typedef unsigned vu4 __attribute__((ext_vector_type(4)));

constexpr int N      = 1 << 24;        // 16,777,216 updates
constexpr int FSHIFT = 14;             // fine tile: 16384 elems = 64 KiB
constexpr int NB     = 256;            // fine bins per batch (per block)
constexpr int NFINE  = 4096;           // fine bins total (16 batches * 256)
constexpr int CHUNK  = 8192;           // records per sort block (64 KiB staging)
constexpr int FCAP   = 4608;           // segment capacity (mean ~4160 + ~7 sigma)
constexpr unsigned TM = (1u << FSHIFT) - 1u;
constexpr unsigned OVF_CAP = 131072;

// workspace layout
constexpr size_t GC_OFF   = 0;                               // 4096 u32 = 16 KiB
constexpr size_t OVFC_OFF = (size_t)NFINE * 4;               // 16384
constexpr size_t OVF_OFF  = OVFC_OFF + 16;                   // 16400
constexpr size_t REC_OFF  = OVF_OFF + (size_t)OVF_CAP * 8;   // 1,064,976 (16B-al)
constexpr size_t WS_NEED  = REC_OFF + (size_t)NFINE * FCAP * 8;  // ~152 MB

__device__ __forceinline__ void spill(unsigned* ovf_cnt, uint2* ovf,
                                      unsigned g, unsigned v) {
    unsigned oi = atomicAdd(ovf_cnt, 1u);
    if (oi < OVF_CAP) ovf[oi] = make_uint2(g, v);
}

__global__ __launch_bounds__(512, 4) void p1(const float* __restrict__ upd,
                                             const int* __restrict__ msk,
                                             unsigned* __restrict__ gcnt,
                                             uint2* __restrict__ recs,
                                             unsigned* __restrict__ ovf_cnt,
                                             uint2* __restrict__ ovf) {
    __shared__ uint2 sorted[CHUNK];                       // 64 KiB
    __shared__ unsigned hist[NB], startx[NB], ends[NB], gbase[NB];
    const int tid = threadIdx.x;
    const int q0 = blockIdx.x * (CHUNK / 4);              // base float4 index
    unsigned g[16];                                       // decoded out indices
    unsigned rank[16];                                    // per-record rank in bin
    vf4 u[4];                                             // values (registers)

    if (tid < NB) hist[tid] = 0;
    __syncthreads();
    // pass A: NT load mask+updates (read-once); decode + RANKING histogram
    // (atomic returns arrival rank -> pass B needs no atomics).
#pragma unroll
    for (int k = 0; k < 4; ++k) {
        int q = q0 + k * 512 + tid;
        vi4 m = __builtin_nontemporal_load((const vi4*)msk + q);
        u[k]  = __builtin_nontemporal_load((const vf4*)upd + q);
        int i = q << 2;
        unsigned gb = ((unsigned)(i >> 20) << 22) | (unsigned)(i & 63);
        g[4 * k + 0] = (gb + 0) | (unsigned)(m.x & ~63);
        g[4 * k + 1] = (gb + 1) | (unsigned)(m.y & ~63);
        g[4 * k + 2] = (gb + 2) | (unsigned)(m.z & ~63);
        g[4 * k + 3] = (gb + 3) | (unsigned)(m.w & ~63);
#pragma unroll
        for (int e = 0; e < 4; ++e)
            rank[4 * k + e] =
                atomicAdd(&hist[(g[4 * k + e] >> FSHIFT) & (NB - 1)], 1u);
    }
    __syncthreads();
    // gbase reservation (issued first: global-atomic latency hides under the
    // scan below). Reserve an EVEN number of slots so gbase is always even
    // (pair stores in pass C are then 16B-aligned). batch = q0>>18.
    if (tid < NB)
        gbase[tid] = atomicAdd(&gcnt[(unsigned)(q0 >> 18) * NB + tid],
                               (hist[tid] + 1u) & ~1u);
    // single-wave exclusive scan over NB=256 bins: wave 0, 4 bins/lane,
    // 6-step shfl_up inclusive scan of per-lane totals.
    if (tid < 64) {
        unsigned h0 = hist[4 * tid + 0], h1 = hist[4 * tid + 1];
        unsigned h2 = hist[4 * tid + 2], h3 = hist[4 * tid + 3];
        unsigned s1 = h0 + h1, s2 = s1 + h2, tot = s2 + h3;
        unsigned incl = tot;
#pragma unroll
        for (int d = 1; d < 64; d <<= 1) {
            unsigned t = __shfl_up(incl, d, 64);
            if (tid >= d) incl += t;
        }
        unsigned base = incl - tot;                       // exclusive base
        startx[4 * tid + 0] = base;
        startx[4 * tid + 1] = base + h0;
        startx[4 * tid + 2] = base + s1;
        startx[4 * tid + 3] = base + s2;
        ends[4 * tid + 0]   = base + h0;
        ends[4 * tid + 1]   = base + s1;
        ends[4 * tid + 2]   = base + s2;
        ends[4 * tid + 3]   = base + tot;
    }
    __syncthreads();
    // pass B: atomic-free placement from registers
#pragma unroll
    for (int k = 0; k < 4; ++k) {
        float v[4] = { u[k].x, u[k].y, u[k].z, u[k].w };
#pragma unroll
        for (int e = 0; e < 4; ++e) {
            unsigned gg = g[4 * k + e];
            unsigned c = (gg >> FSHIFT) & (NB - 1);
            sorted[startx[c] + rank[4 * k + e]] =
                make_uint2(gg, __float_as_uint(v[e]));
        }
    }
    __syncthreads();
    // pass C: ALIGNED paired copy-out. A thread owns the pair starting at
    // run-relative offset rro = j - startx[c] when rro is even; slot
    // s = gbase[c] + rro is even -> 16B-aligned. Odd-length runs emit a
    // dummy (same g, +0.0f) record into the reserved pad slot.
    for (int j = tid; j < CHUNK; j += 512) {
        uint2 r0 = sorted[j];
        unsigned f = r0.x >> FSHIFT;                      // global fine id
        unsigned c = f & (NB - 1);
        unsigned rro = (unsigned)j - startx[c];
        if (rro & 1u) continue;                           // partner of j-1
        unsigned s = gbase[c] + rro;                      // even
        bool pair = ((unsigned)(j + 1) < ends[c]);        // j+1 in same run
        uint2 r1 = pair ? sorted[j + 1] : make_uint2(r0.x, 0u);
        if (s + 1 < (unsigned)FCAP) {
            vu4 rr; rr.x = r0.x; rr.y = r0.y; rr.z = r1.x; rr.w = r1.y;
            *(vu4*)(recs + (size_t)f * FCAP + s) = rr;    // 16B-aligned
        } else {
            if (s < (unsigned)FCAP) recs[(size_t)f * FCAP + s] = r0;
            else spill(ovf_cnt, ovf, r0.x, r0.y);
            if (pair) spill(ovf_cnt, ovf, r1.x, r1.y);    // dummy may be dropped
        }
    }
}

__global__ __launch_bounds__(512, 4) void p3(const uint2* __restrict__ recs,
                                             const unsigned* __restrict__ gcnt,
                                             float* __restrict__ out) {
    __shared__ float tile[1 << FSHIFT];                   // 64 KiB
    const int tid = threadIdx.x;
    const unsigned fi = blockIdx.x;
    const int n = (int)min(gcnt[fi], (unsigned)FCAP);     // always even
    const vu4* __restrict__ seg4 = (const vu4*)(recs + (size_t)fi * FCAP);

    // prefetch segment as record-PAIRS into registers (static indexing, stays
    // in VGPRs); loads fill while we zero the tile below.
    vu4 ra, rb, rc, rd, re;
#define PF(R, K) { int ii = tid + (K) * 512;                                   \
    if (2 * ii < n) R = seg4[ii]; }
    PF(ra, 0) PF(rb, 1) PF(rc, 2) PF(rd, 3) PF(re, 4)
#undef PF

    vf4* t4 = (vf4*)tile;
    const vf4 z4 = { 0.f, 0.f, 0.f, 0.f };
#pragma unroll
    for (int k = 0; k < (1 << FSHIFT) / 4 / 512; ++k)     // 8 float4 iters
        t4[tid + k * 512] = z4;
    __syncthreads();

#define RP(R, K) { int ii = tid + (K) * 512;                                   \
    if (2 * ii < n) {                                                          \
        atomicAdd(&tile[R.x & TM], __uint_as_float(R.y));                      \
        atomicAdd(&tile[R.z & TM], __uint_as_float(R.w)); } }
    RP(ra, 0) RP(rb, 1) RP(rc, 2) RP(rd, 3) RP(re, 4)
#undef RP
    __syncthreads();

    vf4* o = (vf4*)(out + ((size_t)fi << FSHIFT));
#pragma unroll
    for (int k = 0; k < (1 << FSHIFT) / 4 / 512; ++k)
        __builtin_nontemporal_store(t4[tid + k * 512], o + tid + k * 512);
}

__global__ __launch_bounds__(256) void p4(const unsigned* __restrict__ ovf_cnt,
                                          const uint2* __restrict__ ovf,
                                          float* __restrict__ out) {
    unsigned n = min(*ovf_cnt, OVF_CAP);
    for (unsigned i = blockIdx.x * 256 + threadIdx.x; i < n; i += gridDim.x * 256)
        atomicAdd(out + ovf[i].x, __uint_as_float(ovf[i].y));
}

// ---- fallback (ws too small): known-correct direct path ----
__global__ __launch_bounds__(256) void zero_out(float4* __restrict__ out4) {
    size_t i = (size_t)blockIdx.x * 256 + threadIdx.x;
    size_t stride = (size_t)gridDim.x * 256;
    for (size_t k = i; k < (size_t)N; k += stride)
        out4[k] = make_float4(0.f, 0.f, 0.f, 0.f);
}
__global__ __launch_bounds__(256) void unpool_scatter(
        const float4* __restrict__ upd4, const int4* __restrict__ msk4,
        float* __restrict__ out) {
    int i4 = blockIdx.x * 256 + threadIdx.x;
    int i  = i4 << 2;
    float4 u = upd4[i4];
    int4   m = msk4[i4];
    float* outb = out + ((size_t)(i >> 20) << 22);
    int f = i & 63;
    atomicAdd(outb + ((m.x & ~63) | (f + 0)), u.x);
    atomicAdd(outb + ((m.y & ~63) | (f + 1)), u.y);
    atomicAdd(outb + ((m.z & ~63) | (f + 2)), u.z);
    atomicAdd(outb + ((m.w & ~63) | (f + 3)), u.w);
}

extern "C" void kernel_launch(void* const* d_in, const int* in_sizes, int n_in,
                              void* d_out, int out_size, void* d_ws, size_t ws_size,
                              hipStream_t stream) {
    const float* updates = (const float*)d_in[0];
    const int*   mask    = (const int*)d_in[1];
    float*       out     = (float*)d_out;

    if (ws_size >= WS_NEED) {
        char* ws = (char*)d_ws;
        unsigned* gcnt    = (unsigned*)(ws + GC_OFF);
        unsigned* ovf_cnt = (unsigned*)(ws + OVFC_OFF);
        uint2*    ovf     = (uint2*)(ws + OVF_OFF);
        uint2*    recs    = (uint2*)(ws + REC_OFF);

        (void)hipMemsetAsync(ws, 0, OVF_OFF, stream);     // gcnt + ovf_cnt
        p1<<<N / CHUNK, 512, 0, stream>>>(updates, mask, gcnt, recs, ovf_cnt, ovf);
        p3<<<NFINE, 512, 0, stream>>>(recs, gcnt, out);
        p4<<<64, 256, 0, stream>>>(ovf_cnt, ovf, out);
    } else {
        zero_out<<<8192, 256, 0, stream>>>((float4*)out);
        unpool_scatter<<<N / 4 / 256, 256, 0, stream>>>(
            (const float4*)updates, (const int4*)mask, out);
    }
}